// Round 1
// baseline (492.135 us; speedup 1.0000x reference)
//
#include <hip/hip_runtime.h>

#define NN 4096      // reviews
#define LL 128       // tokens
#define DD 200       // word dim
#define AA 32        // aspects
#define NEG 5
#define BB 1024      // users/items
#define FF 16384     // B*H flat history
#define CHUNK_F4 3200   // 64 rows * 50 float4

// workspace layout (float offsets)
#define WS_RS    0
#define WS_USUM  (NN*DD)                  // 819200
#define WS_ISUM  (WS_USUM + BB*DD)
#define WS_UCNT  (WS_ISUM + BB*DD)
#define WS_ICNT  (WS_UCNT + BB)
#define WS_ACC   (WS_ICNT + BB)           // [0]=J_sum [1]=U_mean [2]=RL_sum
#define WS_TT    (WS_ACC + 16)            // transposed T (32 x 200)
#define WS_TOTAL (WS_TT + AA*DD)

__device__ __forceinline__ float wave_sum(float v){
#pragma unroll
  for (int m = 32; m > 0; m >>= 1) v += __shfl_xor(v, m, 64);
  return v;
}
__device__ __forceinline__ float wave_max(float v){
#pragma unroll
  for (int m = 32; m > 0; m >>= 1) v = fmaxf(v, __shfl_xor(v, m, 64));
  return v;
}

__global__ void k_transpose_T(const float* __restrict__ T_w, float* __restrict__ Tt){
  int i = blockIdx.x * 256 + threadIdx.x;
  if (i < DD * AA){ int d = i / AA, a = i % AA; Tt[a * DD + d] = T_w[i]; }
}

// ---- main per-review kernel -------------------------------------------------
// LDS layout (floats):
//   [0,12800)      flat   : e_w chunk (64 rows x 200)
//   [12800,13000)  rp_r   : review_positive, later reused as r_s
//   [13000,13200)  y_zp   : y = rp@M, later reused as z_s partials
//   [13200,13328)  dxax   : dx logits, softmax'd in place -> ax
//   [13328,13528)  zsm    : z_s
//   [13528,13568)  tail   : logits/p (32) + scalars (8)
__device__ __forceinline__ void stage_chunk(float* flat, const int* hrow, int c,
                                            const float* __restrict__ word_emb, int t){
  float4* f4 = (float4*)flat;
  for (int q = t; q < CHUNK_F4; q += 512){
    int lr = q / 50;
    int d4 = q - lr * 50;
    int row = hrow[c * 64 + lr];
    f4[q] = ((const float4*)(word_emb + (size_t)row * DD))[d4];
  }
}

__global__ __launch_bounds__(512, 6)
void k_main(const int* __restrict__ hist, const float* __restrict__ rev_pos,
            const float* __restrict__ rev_neg, const float* __restrict__ word_emb,
            const float* __restrict__ M_w, const float* __restrict__ W_w,
            const float* __restrict__ W_b, const float* __restrict__ Tt,
            float* __restrict__ rs_out, float* __restrict__ acc)
{
  __shared__ __align__(16) float smem[13568];
  float* flat = smem;
  float* rp_r = smem + 12800;
  float* y_zp = smem + 13000;
  float* dxax = smem + 13200;
  float* zsm  = smem + 13328;
  float* lsps = smem + 13528;   // 32
  float* sc   = smem + 13560;   // 8

  const int n = blockIdx.x;
  const int t = threadIdx.x;
  const int w = t >> 6, j = t & 63;
  const int* hrow = hist + n * LL;

  if (t < DD) rp_r[t] = rev_pos[n * DD + t];
  __syncthreads();

  // y[k] = sum_d rp[d] * M_w[d*DD + k]   (coalesced over k)
  if (t < DD){
    float a = 0.f;
#pragma unroll 8
    for (int d = 0; d < DD; ++d) a += rp_r[d] * M_w[d * DD + t];
    y_zp[t] = a;
  }
  __syncthreads();

  // ---- chunk 0: stage + dx rows 0..63
  stage_chunk(flat, hrow, 0, word_emb, t);
  __syncthreads();
#pragma unroll
  for (int r8 = 0; r8 < 8; ++r8){
    int ll = w * 8 + r8, base = ll * DD;
    float p = flat[base + j] * y_zp[j]
            + flat[base + 64 + j] * y_zp[64 + j]
            + flat[base + 128 + j] * y_zp[128 + j];
    if (j < 8) p += flat[base + 192 + j] * y_zp[192 + j];
    p = wave_sum(p);
    if (j == 0) dxax[ll] = p;
  }
  __syncthreads();

  // ---- chunk 1: stage + dx rows 64..127
  stage_chunk(flat, hrow, 1, word_emb, t);
  __syncthreads();
#pragma unroll
  for (int r8 = 0; r8 < 8; ++r8){
    int ll = w * 8 + r8, base = ll * DD;
    float p = flat[base + j] * y_zp[j]
            + flat[base + 64 + j] * y_zp[64 + j]
            + flat[base + 128 + j] * y_zp[128 + j];
    if (j < 8) p += flat[base + 192 + j] * y_zp[192 + j];
    p = wave_sum(p);
    if (j == 0) dxax[64 + ll] = p;
  }
  __syncthreads();

  // ---- softmax over 128 logits (wave 0, in place)
  if (w == 0){
    float a0 = dxax[j], a1 = dxax[j + 64];
    float M = wave_max(fmaxf(a0, a1));
    float e0 = __expf(a0 - M), e1 = __expf(a1 - M);
    float S = wave_sum(e0 + e1);
    float inv = 1.f / S;
    dxax[j] = e0 * inv; dxax[j + 64] = e1 * inv;
  }
  __syncthreads();

  // ---- z_s for chunk 1 (flat currently holds rows 64..127 == flat idx [12800,25600)
  //      -> d2 in [100,200)).  z_s[d2] = sum_l2 flat[d2*128+l2]*ax[l2]
  if (t < 200){
    int d2l = t >> 1, half = t & 1;
    int fb = d2l * 128 + half * 64, ab = half * 64;
    float a = 0.f;
#pragma unroll 4
    for (int i = 0; i < 64; ++i){
      int l2 = (i + t) & 63;           // rotation: bank-conflict-free
      a += flat[fb + l2] * dxax[ab + l2];
    }
    y_zp[t] = a;                       // y dead now; reuse as partials
  }
  __syncthreads();
  if (t < 100) zsm[100 + t] = y_zp[2 * t] + y_zp[2 * t + 1];
  __syncthreads();

  // ---- re-stage chunk 0, z_s for d2 in [0,100)
  stage_chunk(flat, hrow, 0, word_emb, t);
  __syncthreads();
  if (t < 200){
    int d2l = t >> 1, half = t & 1;
    int fb = d2l * 128 + half * 64, ab = half * 64;
    float a = 0.f;
#pragma unroll 4
    for (int i = 0; i < 64; ++i){
      int l2 = (i + t) & 63;
      a += flat[fb + l2] * dxax[ab + l2];
    }
    y_zp[t] = a;
  }
  __syncthreads();
  if (t < 100) zsm[t] = y_zp[2 * t] + y_zp[2 * t + 1];
  __syncthreads();

  // ---- aspect logits: wave w computes a = w*4..w*4+3 (coalesced W_w reads)
#pragma unroll
  for (int aa = 0; aa < 4; ++aa){
    int a = w * 4 + aa;
    const float* Wr = W_w + a * DD;
    float p = zsm[j] * Wr[j] + zsm[j + 64] * Wr[j + 64] + zsm[j + 128] * Wr[j + 128];
    if (j < 8) p += zsm[j + 192] * Wr[j + 192];
    p = wave_sum(p);
    if (j == 0) lsps[a] = p + W_b[a];
  }
  __syncthreads();

  // ---- softmax over 32 aspects (wave 0, in place)
  if (w == 0){
    float v = (j < 32) ? lsps[j] : -3.0e38f;
    float M = wave_max(v);
    float e = __expf(v - M);
    float S = wave_sum(e);
    if (j < 32) lsps[j] = e / S;
  }
  __syncthreads();

  // ---- r_s[d] = sum_a p[a] * T[d][a]  via transposed Tt (coalesced)
  if (t < DD){
    float a = 0.f;
#pragma unroll
    for (int q = 0; q < AA; ++q) a += lsps[q] * Tt[q * DD + t];
    rp_r[t] = a;                       // rp dead; reuse as r
    rs_out[n * DD + t] = a;
  }
  __syncthreads();

  // ---- c1 = cos(r, z) (wave 0)
  if (w == 0){
    float rr = 0, zz = 0, rz = 0;
    for (int k = j; k < DD; k += 64){
      float rv = rp_r[k], zv = zsm[k];
      rr += rv * rv; zz += zv * zv; rz += rv * zv;
    }
    rr = wave_sum(rr); zz = wave_sum(zz); rz = wave_sum(rz);
    if (j == 0){
      float nr = fmaxf(sqrtf(rr), 1e-12f);
      float nz = fmaxf(sqrtf(zz), 1e-12f);
      sc[0] = rz / (nr * nz);          // c1
      sc[1] = nr;
    }
  }
  __syncthreads();

  // ---- c2 over 5 negatives (waves 0..4), hinge accumulate
  if (w < NEG){
    const float* neg = rev_neg + ((size_t)n * NEG + w) * DD;
    float nn = 0, dr = 0;
    for (int k = j; k < DD; k += 64){
      float v = neg[k];
      nn += v * v; dr += v * rp_r[k];
    }
    nn = wave_sum(nn); dr = wave_sum(dr);
    if (j == 0){
      float c2 = dr / (fmaxf(sqrtf(nn), 1e-12f) * sc[1]);
      sc[2 + w] = fmaxf(0.f, c2 - sc[0]);
    }
  }
  __syncthreads();
  if (t == 0) atomicAdd(&acc[0], sc[2] + sc[3] + sc[4] + sc[5] + sc[6]);
}

// ---- U loss: mean((Tn^T Tn - I)^2), Tn = column-normalized T --------------
__global__ __launch_bounds__(1024)
void k_uloss(const float* __restrict__ T_w, float* __restrict__ acc){
  __shared__ float Tl[AA * 201];   // transposed, stride 201 => conflict-free
  __shared__ float nrm[AA];
  __shared__ float wred[16];
  int t = threadIdx.x;
  for (int i = t; i < DD * AA; i += 1024){
    int d = i >> 5, a = i & 31;
    Tl[a * 201 + d] = T_w[i];
  }
  __syncthreads();
  if (t < AA){
    float s = 0;
    for (int d = 0; d < DD; ++d){ float v = Tl[t * 201 + d]; s += v * v; }
    nrm[t] = fmaxf(sqrtf(s), 1e-12f);
  }
  __syncthreads();
  int a = t >> 5, b = t & 31;
  float dot = 0;
#pragma unroll 4
  for (int d = 0; d < DD; ++d) dot += Tl[a * 201 + d] * Tl[b * 201 + d];
  float g = dot / (nrm[a] * nrm[b]) - (a == b ? 1.f : 0.f);
  float v = wave_sum(g * g);
  if ((t & 63) == 0) wred[t >> 6] = v;
  __syncthreads();
  if (t == 0){
    float s = 0;
    for (int k = 0; k < 16; ++k) s += wred[k];
    acc[1] = s / (float)(AA * AA);
  }
}

// ---- segment mean scatter (run-length compressed atomics) ------------------
__device__ __forceinline__ void seg_side(const int* __restrict__ idx, const int* __restrict__ seg,
                                         const float* __restrict__ rs,
                                         float* __restrict__ sum, float* __restrict__ cnt,
                                         int f0, int t){
  int cur = seg[f0];
  float acc = 0.f; int c = 0;
  for (int k = 0; k < 16; ++k){
    int f = f0 + k;
    int s = seg[f];
    if (s != cur){
      if (t < DD) atomicAdd(&sum[(size_t)cur * DD + t], acc);
      if (t == 0) atomicAdd(&cnt[cur], (float)c);
      acc = 0.f; c = 0; cur = s;
    }
    if (t < DD) acc += rs[(size_t)idx[f] * DD + t];
    c++;
  }
  if (t < DD) atomicAdd(&sum[(size_t)cur * DD + t], acc);
  if (t == 0) atomicAdd(&cnt[cur], (float)c);
}

__global__ __launch_bounds__(256)
void k_seg(const int* __restrict__ u_idx, const int* __restrict__ u_seg,
           const int* __restrict__ i_idx, const int* __restrict__ i_seg,
           const float* __restrict__ rs,
           float* __restrict__ u_sum, float* __restrict__ u_cnt,
           float* __restrict__ i_sum, float* __restrict__ i_cnt){
  int t = threadIdx.x;
  int f0 = blockIdx.x * 16;
  seg_side(u_idx, u_seg, rs, u_sum, u_cnt, f0, t);
  seg_side(i_idx, i_seg, rs, i_sum, i_cnt, f0, t);
}

// ---- rating loss -----------------------------------------------------------
__global__ __launch_bounds__(64)
void k_rating(const float* __restrict__ u_sum, const float* __restrict__ u_cnt,
              const float* __restrict__ i_sum, const float* __restrict__ i_cnt,
              const float* __restrict__ label, float* __restrict__ acc){
  int b = blockIdx.x, j = threadIdx.x;
  float d = 0;
  for (int k = j; k < DD; k += 64) d += u_sum[b * DD + k] * i_sum[b * DD + k];
  d = wave_sum(d);
  if (j == 0){
    float pred = d / (u_cnt[b] * i_cnt[b]) + 3.5f;
    float e = pred - label[b];
    atomicAdd(&acc[2], e * e);
  }
}

__global__ void k_final(const float* __restrict__ acc, float* __restrict__ out){
  if (threadIdx.x == 0){
    float J = acc[0] / (float)(NN * NEG);
    float U = acc[1];
    float R = acc[2] / (float)BB;
    float abae = U + J;
    out[0] = R + abae;
    out[1] = R;
    out[2] = abae;
  }
}

extern "C" void kernel_launch(void* const* d_in, const int* in_sizes, int n_in,
                              void* d_out, int out_size, void* d_ws, size_t ws_size,
                              hipStream_t stream){
  const int*   hist     = (const int*)  d_in[0];
  const float* rev_pos  = (const float*)d_in[1];
  const float* rev_neg  = (const float*)d_in[2];
  // d_in[3]=user, d_in[4]=item: unused by the reference
  const float* label    = (const float*)d_in[5];
  const int*   u_idx    = (const int*)  d_in[6];
  const int*   u_seg    = (const int*)  d_in[7];
  const int*   i_idx    = (const int*)  d_in[8];
  const int*   i_seg    = (const int*)  d_in[9];
  const float* word_emb = (const float*)d_in[10];
  const float* M_w      = (const float*)d_in[11];
  const float* W_w      = (const float*)d_in[12];
  const float* W_b      = (const float*)d_in[13];
  const float* T_w      = (const float*)d_in[14];

  float* ws   = (float*)d_ws;
  float* rs   = ws + WS_RS;
  float* usum = ws + WS_USUM;
  float* isum = ws + WS_ISUM;
  float* ucnt = ws + WS_UCNT;
  float* icnt = ws + WS_ICNT;
  float* accp = ws + WS_ACC;
  float* Tt   = ws + WS_TT;

  // zero accumulators + segment sums (ws is poisoned before every launch)
  hipMemsetAsync(usum, 0, (size_t)(WS_TT - WS_USUM) * sizeof(float), stream);

  k_transpose_T<<<(DD * AA + 255) / 256, 256, 0, stream>>>(T_w, Tt);
  k_main<<<NN, 512, 0, stream>>>(hist, rev_pos, rev_neg, word_emb, M_w, W_w, W_b,
                                 Tt, rs, accp);
  k_uloss<<<1, 1024, 0, stream>>>(T_w, accp);
  k_seg<<<FF / 16, 256, 0, stream>>>(u_idx, u_seg, i_idx, i_seg, rs,
                                     usum, ucnt, isum, icnt);
  k_rating<<<BB, 64, 0, stream>>>(usum, ucnt, isum, icnt, label, accp);
  k_final<<<1, 1, 0, stream>>>(accp, (float*)d_out);
}

// Round 2
// 370.157 us; speedup vs baseline: 1.3295x; 1.3295x over previous
//
#include <hip/hip_runtime.h>

#define NN 4096      // reviews
#define LL 128       // tokens
#define DD 200       // word dim
#define AA 32        // aspects
#define NEG 5
#define BB 1024      // users/items
#define FF 16384     // B*H flat history

// workspace layout (float offsets)
#define WS_RS    0
#define WS_Y     (NN*DD)
#define WS_USUM  (WS_Y + NN*DD)
#define WS_ISUM  (WS_USUM + BB*DD)
#define WS_UCNT  (WS_ISUM + BB*DD)
#define WS_ICNT  (WS_UCNT + BB)
#define WS_ACC   (WS_ICNT + BB)           // [0]=J_sum [1]=U_mean [2]=RL_sum
#define WS_TT    (WS_ACC + 16)            // transposed T (32 x 200)

__device__ __forceinline__ float wave_sum(float v){
#pragma unroll
  for (int m = 32; m > 0; m >>= 1) v += __shfl_xor(v, m, 64);
  return v;
}
__device__ __forceinline__ float half_sum(float v){   // reduce within 32-lane half
#pragma unroll
  for (int m = 16; m > 0; m >>= 1) v += __shfl_xor(v, m, 64);
  return v;
}
__device__ __forceinline__ float wave_max(float v){
#pragma unroll
  for (int m = 32; m > 0; m >>= 1) v = fmaxf(v, __shfl_xor(v, m, 64));
  return v;
}

__global__ void k_transpose_T(const float* __restrict__ T_w, float* __restrict__ Tt){
  int i = blockIdx.x * 256 + threadIdx.x;
  if (i < DD * AA){ int d = i / AA, a = i % AA; Tt[a * DD + d] = T_w[i]; }
}

// ---- Y = rev_pos @ M  (y[n][k] = sum_d rp[n][d]*M[d][k]) -------------------
__global__ __launch_bounds__(256)
void k_y(const float* __restrict__ rp, const float* __restrict__ M,
         float* __restrict__ Y){
  __shared__ float rpl[16 * DD];
  int t = threadIdx.x, n0 = blockIdx.x * 16;
  for (int i = t; i < 16 * DD; i += 256) rpl[i] = rp[n0 * DD + i];
  __syncthreads();
  if (t < DD){
    float acc[16];
#pragma unroll
    for (int i = 0; i < 16; ++i) acc[i] = 0.f;
    for (int d = 0; d < DD; ++d){
      float m = M[d * DD + t];
#pragma unroll
      for (int i = 0; i < 16; ++i) acc[i] += rpl[i * DD + d] * m;
    }
#pragma unroll
    for (int i = 0; i < 16; ++i) Y[(size_t)(n0 + i) * DD + t] = acc[i];
  }
}

// ---- main per-review kernel: no e_w staging, direct-global streaming -------
// LDS (floats): y_l[0,200) | dxax[208,336) | zsm[336,536) | r_l[536,736)
//               lsps[736,768) | sc[768,776) | hrowl(int)[776,904)
__global__ __launch_bounds__(256, 8)
void k_main(const int* __restrict__ hist, const float* __restrict__ Yg,
            const float* __restrict__ rev_neg, const float* __restrict__ word_emb,
            const float* __restrict__ W_w, const float* __restrict__ W_b,
            const float* __restrict__ Tt,
            float* __restrict__ rs_out, float* __restrict__ acc)
{
  __shared__ __align__(16) float smem[904];
  float* y_l  = smem;
  float* dxax = smem + 208;
  float* zsm  = smem + 336;
  float* r_l  = smem + 536;
  float* lsps = smem + 736;
  float* sc   = smem + 768;
  int*   hrowl= (int*)(smem + 776);

  const int n = blockIdx.x;
  const int t = threadIdx.x;
  const int w = t >> 6, j = t & 63;

  if (t < DD) y_l[t] = Yg[(size_t)n * DD + t];
  if (t < LL) hrowl[t] = hist[(size_t)n * LL + t];
  __syncthreads();

  // ---- dx[l] = dot(e_w[l], y) : wave per row, stream from global ----------
  float4 y4 = make_float4(0.f, 0.f, 0.f, 0.f);
  if (j < 50) y4 = *(const float4*)(y_l + 4 * j);
#pragma unroll 4
  for (int k = 0; k < 32; ++k){
    int l = k * 4 + w;
    float p = 0.f;
    if (j < 50){
      int row = hrowl[l];
      float4 g = *(const float4*)(word_emb + (size_t)row * DD + 4 * j);
      p = g.x * y4.x + g.y * y4.y + g.z * y4.z + g.w * y4.w;
    }
    p = wave_sum(p);
    if (j == 0) dxax[l] = p;
  }
  __syncthreads();

  // ---- softmax over 128 logits (wave 0, in place) -------------------------
  if (w == 0){
    float a0 = dxax[j], a1 = dxax[j + 64];
    float M = wave_max(fmaxf(a0, a1));
    float e0 = __expf(a0 - M), e1 = __expf(a1 - M);
    float S = wave_sum(e0 + e1);
    float inv = 1.f / S;
    dxax[j] = e0 * inv; dxax[j + 64] = e1 * inv;
  }
  __syncthreads();

  // ---- z[d2] = sum_l2 flat[d2*128+l2]*ax[l2] ------------------------------
  // flat idx f = d2*128+4*jq spans <=2 word_emb rows; float4 never straddles.
  {
    const int h = j >> 5, jq = j & 31;
    float4 ax4 = ((const float4*)dxax)[jq];
#pragma unroll 2
    for (int k = 0; k < 25; ++k){
      int d2 = k * 8 + w * 2 + h;
      unsigned f = (unsigned)d2 * 128u + 4u * (unsigned)jq;
      unsigned r = f / 200u;
      unsigned c = f - r * 200u;
      int row = hrowl[r];
      float4 g = *(const float4*)(word_emb + (size_t)row * DD + c);
      float p = g.x * ax4.x + g.y * ax4.y + g.z * ax4.z + g.w * ax4.w;
      p = half_sum(p);
      if (jq == 0) zsm[d2] = p;
    }
  }
  __syncthreads();

  // ---- aspect logits: wave w computes a = w*8..w*8+7 ----------------------
#pragma unroll
  for (int aa = 0; aa < 8; ++aa){
    int a = w * 8 + aa;
    const float* Wr = W_w + a * DD;
    float p = zsm[j] * Wr[j] + zsm[j + 64] * Wr[j + 64] + zsm[j + 128] * Wr[j + 128];
    if (j < 8) p += zsm[j + 192] * Wr[j + 192];
    p = wave_sum(p);
    if (j == 0) lsps[a] = p + W_b[a];
  }
  __syncthreads();

  // ---- softmax over 32 aspects (wave 0) -----------------------------------
  if (w == 0){
    float v = (j < 32) ? lsps[j] : -3.0e38f;
    float M = wave_max(v);
    float e = __expf(v - M);
    float S = wave_sum(e);
    if (j < 32) lsps[j] = e / S;
  }
  __syncthreads();

  // ---- r_s[d] = sum_a p[a]*T[d][a] via transposed Tt ----------------------
  if (t < DD){
    float a = 0.f;
#pragma unroll
    for (int q = 0; q < AA; ++q) a += lsps[q] * Tt[q * DD + t];
    r_l[t] = a;
    rs_out[(size_t)n * DD + t] = a;
  }
  __syncthreads();

  // ---- c1 = cos(r, z) (wave 0) --------------------------------------------
  if (w == 0){
    float rr = 0, zz = 0, rz = 0;
    for (int k = j; k < DD; k += 64){
      float rv = r_l[k], zv = zsm[k];
      rr += rv * rv; zz += zv * zv; rz += rv * zv;
    }
    rr = wave_sum(rr); zz = wave_sum(zz); rz = wave_sum(rz);
    if (j == 0){
      float nr = fmaxf(sqrtf(rr), 1e-12f);
      float nz = fmaxf(sqrtf(zz), 1e-12f);
      sc[0] = rz / (nr * nz);          // c1
      sc[1] = nr;
    }
  }
  __syncthreads();

  // ---- c2 over 5 negatives (waves 0..3; wave 0 also takes #4) -------------
  for (int g5 = w; g5 < NEG; g5 += 4){
    const float* neg = rev_neg + ((size_t)n * NEG + g5) * DD;
    float nn = 0, dr = 0;
    for (int k = j; k < DD; k += 64){
      float v = neg[k];
      nn += v * v; dr += v * r_l[k];
    }
    nn = wave_sum(nn); dr = wave_sum(dr);
    if (j == 0){
      float c2 = dr / (fmaxf(sqrtf(nn), 1e-12f) * sc[1]);
      sc[2 + g5] = fmaxf(0.f, c2 - sc[0]);
    }
  }
  __syncthreads();
  if (t == 0) atomicAdd(&acc[0], sc[2] + sc[3] + sc[4] + sc[5] + sc[6]);
}

// ---- U loss: mean((Tn^T Tn - I)^2), Tn = column-normalized T --------------
__global__ __launch_bounds__(1024)
void k_uloss(const float* __restrict__ T_w, float* __restrict__ acc){
  __shared__ float Tl[AA * 201];
  __shared__ float nrm[AA];
  __shared__ float wred[16];
  int t = threadIdx.x;
  for (int i = t; i < DD * AA; i += 1024){
    int d = i >> 5, a = i & 31;
    Tl[a * 201 + d] = T_w[i];
  }
  __syncthreads();
  if (t < AA){
    float s = 0;
    for (int d = 0; d < DD; ++d){ float v = Tl[t * 201 + d]; s += v * v; }
    nrm[t] = fmaxf(sqrtf(s), 1e-12f);
  }
  __syncthreads();
  int a = t >> 5, b = t & 31;
  float dot = 0;
#pragma unroll 4
  for (int d = 0; d < DD; ++d) dot += Tl[a * 201 + d] * Tl[b * 201 + d];
  float g = dot / (nrm[a] * nrm[b]) - (a == b ? 1.f : 0.f);
  float v = wave_sum(g * g);
  if ((t & 63) == 0) wred[t >> 6] = v;
  __syncthreads();
  if (t == 0){
    float s = 0;
    for (int k = 0; k < 16; ++k) s += wred[k];
    acc[1] = s / (float)(AA * AA);
  }
}

// ---- segment mean scatter (run-length compressed atomics) ------------------
__device__ __forceinline__ void seg_side(const int* __restrict__ idx, const int* __restrict__ seg,
                                         const float* __restrict__ rs,
                                         float* __restrict__ sum, float* __restrict__ cnt,
                                         int f0, int t){
  int cur = seg[f0];
  float acc = 0.f; int c = 0;
  for (int k = 0; k < 16; ++k){
    int f = f0 + k;
    int s = seg[f];
    if (s != cur){
      if (t < DD) atomicAdd(&sum[(size_t)cur * DD + t], acc);
      if (t == 0) atomicAdd(&cnt[cur], (float)c);
      acc = 0.f; c = 0; cur = s;
    }
    if (t < DD) acc += rs[(size_t)idx[f] * DD + t];
    c++;
  }
  if (t < DD) atomicAdd(&sum[(size_t)cur * DD + t], acc);
  if (t == 0) atomicAdd(&cnt[cur], (float)c);
}

__global__ __launch_bounds__(256)
void k_seg(const int* __restrict__ u_idx, const int* __restrict__ u_seg,
           const int* __restrict__ i_idx, const int* __restrict__ i_seg,
           const float* __restrict__ rs,
           float* __restrict__ u_sum, float* __restrict__ u_cnt,
           float* __restrict__ i_sum, float* __restrict__ i_cnt){
  int t = threadIdx.x;
  int f0 = blockIdx.x * 16;
  seg_side(u_idx, u_seg, rs, u_sum, u_cnt, f0, t);
  seg_side(i_idx, i_seg, rs, i_sum, i_cnt, f0, t);
}

// ---- rating loss -----------------------------------------------------------
__global__ __launch_bounds__(64)
void k_rating(const float* __restrict__ u_sum, const float* __restrict__ u_cnt,
              const float* __restrict__ i_sum, const float* __restrict__ i_cnt,
              const float* __restrict__ label, float* __restrict__ acc){
  int b = blockIdx.x, j = threadIdx.x;
  float d = 0;
  for (int k = j; k < DD; k += 64) d += u_sum[b * DD + k] * i_sum[b * DD + k];
  d = wave_sum(d);
  if (j == 0){
    float pred = d / (u_cnt[b] * i_cnt[b]) + 3.5f;
    float e = pred - label[b];
    atomicAdd(&acc[2], e * e);
  }
}

__global__ void k_final(const float* __restrict__ acc, float* __restrict__ out){
  if (threadIdx.x == 0){
    float J = acc[0] / (float)(NN * NEG);
    float U = acc[1];
    float R = acc[2] / (float)BB;
    float abae = U + J;
    out[0] = R + abae;
    out[1] = R;
    out[2] = abae;
  }
}

extern "C" void kernel_launch(void* const* d_in, const int* in_sizes, int n_in,
                              void* d_out, int out_size, void* d_ws, size_t ws_size,
                              hipStream_t stream){
  const int*   hist     = (const int*)  d_in[0];
  const float* rev_pos  = (const float*)d_in[1];
  const float* rev_neg  = (const float*)d_in[2];
  const float* label    = (const float*)d_in[5];
  const int*   u_idx    = (const int*)  d_in[6];
  const int*   u_seg    = (const int*)  d_in[7];
  const int*   i_idx    = (const int*)  d_in[8];
  const int*   i_seg    = (const int*)  d_in[9];
  const float* word_emb = (const float*)d_in[10];
  const float* M_w      = (const float*)d_in[11];
  const float* W_w      = (const float*)d_in[12];
  const float* W_b      = (const float*)d_in[13];
  const float* T_w      = (const float*)d_in[14];

  float* ws   = (float*)d_ws;
  float* rs   = ws + WS_RS;
  float* Yg   = ws + WS_Y;
  float* usum = ws + WS_USUM;
  float* isum = ws + WS_ISUM;
  float* ucnt = ws + WS_UCNT;
  float* icnt = ws + WS_ICNT;
  float* accp = ws + WS_ACC;
  float* Tt   = ws + WS_TT;

  hipMemsetAsync(usum, 0, (size_t)(WS_TT - WS_USUM) * sizeof(float), stream);

  k_transpose_T<<<(DD * AA + 255) / 256, 256, 0, stream>>>(T_w, Tt);
  k_y<<<NN / 16, 256, 0, stream>>>(rev_pos, M_w, Yg);
  k_uloss<<<1, 1024, 0, stream>>>(T_w, accp);
  k_main<<<NN, 256, 0, stream>>>(hist, Yg, rev_neg, word_emb, W_w, W_b,
                                 Tt, rs, accp);
  k_seg<<<FF / 16, 256, 0, stream>>>(u_idx, u_seg, i_idx, i_seg, rs,
                                     usum, ucnt, isum, icnt);
  k_rating<<<BB, 64, 0, stream>>>(usum, ucnt, isum, icnt, label, accp);
  k_final<<<1, 1, 0, stream>>>(accp, (float*)d_out);
}